// Round 2
// baseline (31944.290 us; speedup 1.0000x reference)
//
#include <hip/hip_runtime.h>
#include <hip/hip_cooperative_groups.h>

namespace cg = cooperative_groups;

#define NEGV (-1000000000.0f)
#define N_ITERS 32

// ---------------- util: u[e] = clip(dot(feats[e], w) + b, -100, -1e-6) ----------------
__global__ __launch_bounds__(256) void util_kernel(
    const float* __restrict__ feats, const float* __restrict__ weight,
    const float* __restrict__ bias, float* __restrict__ u,
    int E, int F)
{
    int e = blockIdx.x * blockDim.x + threadIdx.x;
    if (e >= E) return;
    const float* row = feats + (size_t)e * (size_t)F;
    float acc = 0.0f;
    for (int f = 0; f < F; f += 4) {
        float4 fv = *reinterpret_cast<const float4*>(row + f);
        acc += fv.x * weight[f + 0];
        acc += fv.y * weight[f + 1];
        acc += fv.z * weight[f + 2];
        acc += fv.w * weight[f + 3];
    }
    acc += bias[0];
    acc = fminf(fmaxf(acc, -100.0f), -1e-6f);
    u[e] = acc;
}

// ---------------- cooperative all-in-one iteration kernel ----------------
// dest_mask: int32 (harness canonicalizes bool -> int32)
__global__ __launch_bounds__(256) void iter_kernel(
    const float* __restrict__ u, const int* __restrict__ src,
    const int* __restrict__ dst, const int* __restrict__ dest_mask,
    float* v, float* s, float* prob,
    int N, int E)
{
    cg::grid_group grid = cg::this_grid();
    const int tid = blockIdx.x * blockDim.x + threadIdx.x;
    const int nthreads = gridDim.x * blockDim.x;

    // init: v0 = dest ? 0 : NEG ; s = 0
    for (int n = tid; n < N; n += nthreads) {
        v[n] = dest_mask[n] ? 0.0f : NEGV;
        s[n] = 0.0f;
    }
    __threadfence();
    grid.sync();
    __threadfence();

    for (int it = 0; it < N_ITERS; ++it) {
        // edge pass: s[src] += exp(u + v[dst])
        for (int e = tid; e < E; e += nthreads) {
            float x = u[e] + v[dst[e]];
            atomicAdd(&s[src[e]], __expf(0.0f) == 1.0f ? expf(x) : expf(x));
        }
        __threadfence();
        grid.sync();
        __threadfence();
        // node pass: v = dest ? 0 : (s>0 ? log(s) : NEG); reset s
        for (int n = tid; n < N; n += nthreads) {
            float sv = s[n];
            v[n] = dest_mask[n] ? 0.0f : (sv > 0.0f ? logf(sv) : NEGV);
            s[n] = 0.0f;
        }
        __threadfence();
        grid.sync();
        __threadfence();
    }

    // prob = exp((u + v[dst]) - v[src])   [left-assoc order matches reference]
    for (int e = tid; e < E; e += nthreads) {
        float p = expf((u[e] + v[dst[e]]) - v[src[e]]);
        prob[e] = p;
    }
}

// ---------------- non-cooperative fallback kernels ----------------
__global__ __launch_bounds__(256) void init_pass(
    const int* __restrict__ dest_mask, float* __restrict__ v,
    float* __restrict__ s, int N)
{
    int n = blockIdx.x * blockDim.x + threadIdx.x;
    if (n >= N) return;
    v[n] = dest_mask[n] ? 0.0f : NEGV;
    s[n] = 0.0f;
}

__global__ __launch_bounds__(256) void edge_pass(
    const float* __restrict__ u, const int* __restrict__ src,
    const int* __restrict__ dst, const float* __restrict__ v,
    float* s, int E)
{
    int e = blockIdx.x * blockDim.x + threadIdx.x;
    if (e >= E) return;
    float x = u[e] + v[dst[e]];
    atomicAdd(&s[src[e]], expf(x));
}

__global__ __launch_bounds__(256) void node_pass(
    const int* __restrict__ dest_mask, float* __restrict__ v,
    float* s, int N)
{
    int n = blockIdx.x * blockDim.x + threadIdx.x;
    if (n >= N) return;
    float sv = s[n];
    v[n] = dest_mask[n] ? 0.0f : (sv > 0.0f ? logf(sv) : NEGV);
    s[n] = 0.0f;
}

__global__ __launch_bounds__(256) void prob_pass(
    const float* __restrict__ u, const int* __restrict__ src,
    const int* __restrict__ dst, const float* __restrict__ v,
    float* prob, int E)
{
    int e = blockIdx.x * blockDim.x + threadIdx.x;
    if (e >= E) return;
    prob[e] = expf((u[e] + v[dst[e]]) - v[src[e]]);
}

// ---------------- host ----------------
extern "C" void kernel_launch(void* const* d_in, const int* in_sizes, int n_in,
                              void* d_out, int out_size, void* d_ws, size_t ws_size,
                              hipStream_t stream)
{
    const float* feats     = (const float*)d_in[0];
    const int*   dest_mask = (const int*)d_in[1];   // bool canonicalized to int32
    const int*   edge_index= (const int*)d_in[2];
    // d_in[3] = batch (unused), d_in[4] = n_nodes (device scalar; use in_sizes)
    const float* weight    = (const float*)d_in[5];
    const float* bias      = (const float*)d_in[6];

    const int F = in_sizes[5];
    const int E = in_sizes[2] / 2;
    const int N = in_sizes[1];

    const int* src = edge_index;       // row 0
    const int* dst = edge_index + E;   // row 1

    float* out   = (float*)d_out;
    float* value = out;                         // N floats (doubles as v state)
    float* util  = out + N;                     // E floats (doubles as u)
    float* prob  = out + (size_t)N + (size_t)E; // E floats

    // scratch s: prefer d_ws, else carve from prob region (overwritten only at end)
    float* s = (ws_size >= (size_t)N * sizeof(float)) ? (float*)d_ws : prob;

    // K1: util / u
    {
        int blocks = (E + 255) / 256;
        util_kernel<<<blocks, 256, 0, stream>>>(feats, weight, bias, util, E, F);
    }

    // K2: iterations (+ value + prob)
    int dev = 0;
    hipGetDevice(&dev);
    int coop = 0, numCU = 0, maxAct = 0;
    hipDeviceGetAttribute(&coop, hipDeviceAttributeCooperativeLaunch, dev);
    hipDeviceGetAttribute(&numCU, hipDeviceAttributeMultiprocessorCount, dev);
    hipOccupancyMaxActiveBlocksPerMultiprocessor(&maxAct,
        reinterpret_cast<const void*>(iter_kernel), 256, 0);

    bool launched = false;
    if (coop && maxAct >= 1 && numCU >= 1) {
        int grid = maxAct * numCU;
        if (grid > 2048) grid = 2048;
        void* args[] = {
            (void*)&util, (void*)&src, (void*)&dst, (void*)&dest_mask,
            (void*)&value, (void*)&s, (void*)&prob,
            (void*)&N, (void*)&E
        };
        hipError_t err = hipLaunchCooperativeKernel(
            reinterpret_cast<const void*>(iter_kernel),
            dim3(grid), dim3(256), args, 0, stream);
        launched = (err == hipSuccess);
    }

    if (!launched) {
        // fallback: explicit launch sequence (stream-ordered)
        int nb = (N + 255) / 256;
        int eb = (E + 255) / 256;
        init_pass<<<nb, 256, 0, stream>>>(dest_mask, value, s, N);
        for (int it = 0; it < N_ITERS; ++it) {
            edge_pass<<<eb, 256, 0, stream>>>(util, src, dst, value, s, E);
            node_pass<<<nb, 256, 0, stream>>>(dest_mask, value, s, N);
        }
        prob_pass<<<eb, 256, 0, stream>>>(util, src, dst, value, prob, E);
    }
}

// Round 3
// 21290.840 us; speedup vs baseline: 1.5004x; 1.5004x over previous
//
#include <hip/hip_runtime.h>
#include <hip/hip_cooperative_groups.h>

namespace cg = cooperative_groups;

#define NEGV (-1000000000.0f)
#define N_ITERS 32
#define HIST_BLOCKS 64

// ---------------- util: u[e] = clip(dot(feats[e], w) + b, -100, -1e-6) ----------------
__global__ __launch_bounds__(256) void util_kernel(
    const float* __restrict__ feats, const float* __restrict__ weight,
    const float* __restrict__ bias, float* __restrict__ u,
    int E, int F)
{
    int e = blockIdx.x * blockDim.x + threadIdx.x;
    if (e >= E) return;
    const float* row = feats + (size_t)e * (size_t)F;
    float acc = 0.0f;
    for (int f = 0; f < F; f += 4) {
        float4 fv = *reinterpret_cast<const float4*>(row + f);
        acc += fv.x * weight[f + 0];
        acc += fv.y * weight[f + 1];
        acc += fv.z * weight[f + 2];
        acc += fv.w * weight[f + 3];
    }
    acc += bias[0];
    acc = fminf(fmaxf(acc, -100.0f), -1e-6f);
    u[e] = acc;
}

// ---------------- CSR build: histogram (LDS atomics, per-block node range) ----------------
__global__ __launch_bounds__(256) void hist_kernel(
    const int* __restrict__ src, int* __restrict__ cnt, int N, int E, int NB)
{
    extern __shared__ int lcnt[];
    const int lo = blockIdx.x * NB;
    const int hi = min(N, lo + NB);
    const int nb = hi - lo;
    if (nb <= 0) return;
    for (int i = threadIdx.x; i < nb; i += blockDim.x) lcnt[i] = 0;
    __syncthreads();
    const int stride = blockDim.x;
    for (int e = threadIdx.x; e < E; e += stride) {
        int s = src[e];
        if (s >= lo && s < hi) atomicAdd(&lcnt[s - lo], 1);
    }
    __syncthreads();
    for (int i = threadIdx.x; i < nb; i += blockDim.x) cnt[lo + i] = lcnt[i];
}

// ---------------- single-block exclusive scan: cnt[0..N) -> row_ptr[0..N], row_ptr[N]=E ----
__global__ __launch_bounds__(1024) void scan_kernel(
    const int* __restrict__ cnt, int* __restrict__ row_ptr, int N, int E)
{
    __shared__ int part[1024];
    const int T = 1024;
    const int t = threadIdx.x;
    const int chunk = (N + T - 1) / T;
    const int lo = t * chunk;
    const int hi = min(N, lo + chunk);
    int sum = 0;
    for (int i = lo; i < hi; ++i) sum += cnt[i];
    part[t] = sum;
    __syncthreads();
    // Hillis-Steele inclusive scan
    for (int off = 1; off < T; off <<= 1) {
        int v = part[t];
        if (t >= off) v += part[t - off];
        __syncthreads();
        part[t] = v;
        __syncthreads();
    }
    int run = (t == 0) ? 0 : part[t - 1];
    for (int i = lo; i < hi; ++i) { row_ptr[i] = run; run += cnt[i]; }
    if (t == T - 1) row_ptr[N] = E;
}

// ---------------- scatter: edges grouped by src via LDS cursors ----------------
__global__ __launch_bounds__(256) void scatter_kernel(
    const int* __restrict__ src, const int* __restrict__ dst,
    const int* __restrict__ row_ptr,
    int* __restrict__ dst_perm, int* __restrict__ eidx,
    int N, int E, int NB)
{
    extern __shared__ int curs[];
    const int lo = blockIdx.x * NB;
    const int hi = min(N, lo + NB);
    const int nb = hi - lo;
    if (nb <= 0) return;
    for (int i = threadIdx.x; i < nb; i += blockDim.x) curs[i] = row_ptr[lo + i];
    __syncthreads();
    const int stride = blockDim.x;
    for (int e = threadIdx.x; e < E; e += stride) {
        int s = src[e];
        if (s >= lo && s < hi) {
            int pos = atomicAdd(&curs[s - lo], 1);
            dst_perm[pos] = dst[e];
            eidx[pos] = e;
        }
    }
}

// ---------------- gather u into perm order (in-place over eidx) ----------------
__global__ __launch_bounds__(256) void uperm_kernel(
    const float* __restrict__ u, float* uperm_f, int E)
{
    int j = blockIdx.x * blockDim.x + threadIdx.x;
    if (j >= E) return;
    const int* eidx = (const int*)uperm_f;
    int e = eidx[j];           // read int
    uperm_f[j] = u[e];         // overwrite same slot with float (data-dependent, safe)
}

// ---------------- cooperative atomic-free value iteration ----------------
__global__ __launch_bounds__(256) void value_kernel(
    const int* __restrict__ row_ptr, const int* __restrict__ dst_perm,
    const float* __restrict__ uperm, const int* __restrict__ dest_mask,
    float* va, float* vb,
    const float* __restrict__ u, const int* __restrict__ src,
    const int* __restrict__ dst,
    float* value_out, float* prob,
    int N, int E)
{
    cg::grid_group grid = cg::this_grid();
    const int tid = blockIdx.x * blockDim.x + threadIdx.x;
    const int nthreads = gridDim.x * blockDim.x;
    const int lane8 = tid & 7;
    const int g0 = tid >> 3;
    const int ngroups = nthreads >> 3;

    // init v0
    for (int n = tid; n < N; n += nthreads)
        va[n] = dest_mask[n] ? 0.0f : NEGV;
    __threadfence();
    grid.sync();
    __threadfence();

    float* cur = va;
    float* nxt = vb;
    for (int it = 0; it < N_ITERS; ++it) {
        for (int n = g0; n < N; n += ngroups) {
            int rs = row_ptr[n];
            int re = row_ptr[n + 1];
            float s = 0.0f;
            for (int j = rs + lane8; j < re; j += 8)
                s += expf(uperm[j] + cur[dst_perm[j]]);
            s += __shfl_xor(s, 4, 8);
            s += __shfl_xor(s, 2, 8);
            s += __shfl_xor(s, 1, 8);
            if (lane8 == 0)
                nxt[n] = dest_mask[n] ? 0.0f : (s > 0.0f ? logf(s) : NEGV);
        }
        __threadfence();
        grid.sync();
        __threadfence();
        float* t = cur; cur = nxt; nxt = t;
    }

    // outputs: value = cur ; prob = exp((u + v[dst]) - v[src])
    for (int n = tid; n < N; n += nthreads) value_out[n] = cur[n];
    for (int e = tid; e < E; e += nthreads)
        prob[e] = expf((u[e] + cur[dst[e]]) - cur[src[e]]);
}

// ================= round-2 proven fallback (atomic path) =================
__global__ __launch_bounds__(256) void iter_kernel(
    const float* __restrict__ u, const int* __restrict__ src,
    const int* __restrict__ dst, const int* __restrict__ dest_mask,
    float* v, float* s, float* prob,
    int N, int E)
{
    cg::grid_group grid = cg::this_grid();
    const int tid = blockIdx.x * blockDim.x + threadIdx.x;
    const int nthreads = gridDim.x * blockDim.x;
    for (int n = tid; n < N; n += nthreads) {
        v[n] = dest_mask[n] ? 0.0f : NEGV;
        s[n] = 0.0f;
    }
    __threadfence();
    grid.sync();
    __threadfence();
    for (int it = 0; it < N_ITERS; ++it) {
        for (int e = tid; e < E; e += nthreads) {
            float x = u[e] + v[dst[e]];
            atomicAdd(&s[src[e]], expf(x));
        }
        __threadfence();
        grid.sync();
        __threadfence();
        for (int n = tid; n < N; n += nthreads) {
            float sv = s[n];
            v[n] = dest_mask[n] ? 0.0f : (sv > 0.0f ? logf(sv) : NEGV);
            s[n] = 0.0f;
        }
        __threadfence();
        grid.sync();
        __threadfence();
    }
    for (int e = tid; e < E; e += nthreads)
        prob[e] = expf((u[e] + v[dst[e]]) - v[src[e]]);
}

__global__ __launch_bounds__(256) void init_pass(
    const int* __restrict__ dest_mask, float* v, float* s, int N)
{
    int n = blockIdx.x * blockDim.x + threadIdx.x;
    if (n >= N) return;
    v[n] = dest_mask[n] ? 0.0f : NEGV;
    s[n] = 0.0f;
}
__global__ __launch_bounds__(256) void edge_pass(
    const float* __restrict__ u, const int* __restrict__ src,
    const int* __restrict__ dst, const float* __restrict__ v, float* s, int E)
{
    int e = blockIdx.x * blockDim.x + threadIdx.x;
    if (e >= E) return;
    atomicAdd(&s[src[e]], expf(u[e] + v[dst[e]]));
}
__global__ __launch_bounds__(256) void node_pass(
    const int* __restrict__ dest_mask, float* v, float* s, int N)
{
    int n = blockIdx.x * blockDim.x + threadIdx.x;
    if (n >= N) return;
    float sv = s[n];
    v[n] = dest_mask[n] ? 0.0f : (sv > 0.0f ? logf(sv) : NEGV);
    s[n] = 0.0f;
}
__global__ __launch_bounds__(256) void prob_pass(
    const float* __restrict__ u, const int* __restrict__ src,
    const int* __restrict__ dst, const float* __restrict__ v, float* prob, int E)
{
    int e = blockIdx.x * blockDim.x + threadIdx.x;
    if (e >= E) return;
    prob[e] = expf((u[e] + v[dst[e]]) - v[src[e]]);
}

// ---------------- host ----------------
extern "C" void kernel_launch(void* const* d_in, const int* in_sizes, int n_in,
                              void* d_out, int out_size, void* d_ws, size_t ws_size,
                              hipStream_t stream)
{
    const float* feats     = (const float*)d_in[0];
    const int*   dest_mask = (const int*)d_in[1];   // bool canonicalized to int32
    const int*   edge_index= (const int*)d_in[2];
    const float* weight    = (const float*)d_in[5];
    const float* bias      = (const float*)d_in[6];

    const int F = in_sizes[5];
    const int E = in_sizes[2] / 2;
    const int N = in_sizes[1];

    const int* src = edge_index;       // row 0
    const int* dst = edge_index + E;   // row 1

    float* out   = (float*)d_out;
    float* value = out;
    float* util  = out + N;
    float* prob  = out + (size_t)N + (size_t)E;

    // K1: util / u
    {
        int blocks = (E + 255) / 256;
        util_kernel<<<blocks, 256, 0, stream>>>(feats, weight, bias, util, E, F);
    }

    int dev = 0;
    hipGetDevice(&dev);
    int coop = 0, numCU = 0;
    hipDeviceGetAttribute(&coop, hipDeviceAttributeCooperativeLaunch, dev);
    hipDeviceGetAttribute(&numCU, hipDeviceAttributeMultiprocessorCount, dev);

    // ws layout for CSR path
    const size_t need_words = (size_t)(N + 1) + N + (size_t)E + (size_t)E + N + N;
    const size_t need_bytes = need_words * 4;

    bool fast_ok = false;
    if (coop && d_ws != nullptr && ws_size >= need_bytes) {
        int*   row_ptr = (int*)d_ws;             // N+1
        int*   cnt     = row_ptr + (N + 1);      // N
        int*   dstp    = cnt + N;                // E
        float* uperm   = (float*)(dstp + E);     // E (first holds eidx ints)
        float* va      = uperm + E;              // N
        float* vb      = va + N;                 // N
        int*   eidx    = (int*)uperm;

        const int NB = (N + HIST_BLOCKS - 1) / HIST_BLOCKS;
        const size_t lds_bytes = (size_t)NB * 4;

        hist_kernel<<<HIST_BLOCKS, 256, lds_bytes, stream>>>(src, cnt, N, E, NB);
        scan_kernel<<<1, 1024, 0, stream>>>(cnt, row_ptr, N, E);
        scatter_kernel<<<HIST_BLOCKS, 256, lds_bytes, stream>>>(
            src, dst, row_ptr, dstp, eidx, N, E, NB);
        uperm_kernel<<<(E + 255) / 256, 256, 0, stream>>>(util, uperm, E);

        int maxAct = 0;
        hipOccupancyMaxActiveBlocksPerMultiprocessor(&maxAct,
            reinterpret_cast<const void*>(value_kernel), 256, 0);
        int grid = (maxAct > 0 ? maxAct : 4) * (numCU > 0 ? numCU : 256);
        if (grid > 2048) grid = 2048;

        void* args[] = {
            (void*)&row_ptr, (void*)&dstp, (void*)&uperm, (void*)&dest_mask,
            (void*)&va, (void*)&vb,
            (void*)&util, (void*)&src, (void*)&dst,
            (void*)&value, (void*)&prob,
            (void*)&N, (void*)&E
        };
        hipError_t err = hipLaunchCooperativeKernel(
            reinterpret_cast<const void*>(value_kernel),
            dim3(grid), dim3(256), args, 0, stream);
        fast_ok = (err == hipSuccess);
    }

    if (!fast_ok) {
        // round-2 proven fallback
        float* s = (ws_size >= (size_t)N * sizeof(float)) ? (float*)d_ws : prob;
        bool launched = false;
        if (coop) {
            int maxAct = 0;
            hipOccupancyMaxActiveBlocksPerMultiprocessor(&maxAct,
                reinterpret_cast<const void*>(iter_kernel), 256, 0);
            if (maxAct >= 1 && numCU >= 1) {
                int grid = maxAct * numCU;
                if (grid > 2048) grid = 2048;
                void* args[] = {
                    (void*)&util, (void*)&src, (void*)&dst, (void*)&dest_mask,
                    (void*)&value, (void*)&s, (void*)&prob,
                    (void*)&N, (void*)&E
                };
                hipError_t err = hipLaunchCooperativeKernel(
                    reinterpret_cast<const void*>(iter_kernel),
                    dim3(grid), dim3(256), args, 0, stream);
                launched = (err == hipSuccess);
            }
        }
        if (!launched) {
            int nb = (N + 255) / 256;
            int eb = (E + 255) / 256;
            init_pass<<<nb, 256, 0, stream>>>(dest_mask, value, s, N);
            for (int it = 0; it < N_ITERS; ++it) {
                edge_pass<<<eb, 256, 0, stream>>>(util, src, dst, value, s, E);
                node_pass<<<nb, 256, 0, stream>>>(dest_mask, value, s, N);
            }
            prob_pass<<<eb, 256, 0, stream>>>(util, src, dst, value, prob, E);
        }
    }
}

// Round 4
// 5501.067 us; speedup vs baseline: 5.8069x; 3.8703x over previous
//
#include <hip/hip_runtime.h>

#define NEGV (-1000000000.0f)
#define N_ITERS 32
#define HIST_BLOCKS 64

// ---------------- util: u[e] = clip(dot(feats[e], w) + b, -100, -1e-6) ----------------
__global__ __launch_bounds__(256) void util_kernel(
    const float* __restrict__ feats, const float* __restrict__ weight,
    const float* __restrict__ bias, float* __restrict__ u,
    int E, int F)
{
    int e = blockIdx.x * blockDim.x + threadIdx.x;
    if (e >= E) return;
    const float* row = feats + (size_t)e * (size_t)F;
    float acc = 0.0f;
    for (int f = 0; f < F; f += 4) {
        float4 fv = *reinterpret_cast<const float4*>(row + f);
        acc += fv.x * weight[f + 0];
        acc += fv.y * weight[f + 1];
        acc += fv.z * weight[f + 2];
        acc += fv.w * weight[f + 3];
    }
    acc += bias[0];
    acc = fminf(fmaxf(acc, -100.0f), -1e-6f);
    u[e] = acc;
}

// ---------------- CSR build: histogram (LDS atomics, per-block node range) ----------------
__global__ __launch_bounds__(256) void hist_kernel(
    const int* __restrict__ src, int* __restrict__ cnt, int N, int E, int NB)
{
    extern __shared__ int lcnt[];
    const int lo = blockIdx.x * NB;
    const int hi = min(N, lo + NB);
    const int nb = hi - lo;
    if (nb <= 0) return;
    for (int i = threadIdx.x; i < nb; i += blockDim.x) lcnt[i] = 0;
    __syncthreads();
    for (int e = threadIdx.x; e < E; e += blockDim.x) {
        int s = src[e];
        if (s >= lo && s < hi) atomicAdd(&lcnt[s - lo], 1);
    }
    __syncthreads();
    for (int i = threadIdx.x; i < nb; i += blockDim.x) cnt[lo + i] = lcnt[i];
}

// ---------------- single-block exclusive scan: cnt[0..N) -> row_ptr[0..N], row_ptr[N]=E ----
__global__ __launch_bounds__(1024) void scan_kernel(
    const int* __restrict__ cnt, int* __restrict__ row_ptr, int N, int E)
{
    __shared__ int part[1024];
    const int T = 1024;
    const int t = threadIdx.x;
    const int chunk = (N + T - 1) / T;
    const int lo = t * chunk;
    const int hi = min(N, lo + chunk);
    int sum = 0;
    for (int i = lo; i < hi; ++i) sum += cnt[i];
    part[t] = sum;
    __syncthreads();
    for (int off = 1; off < T; off <<= 1) {
        int v = part[t];
        if (t >= off) v += part[t - off];
        __syncthreads();
        part[t] = v;
        __syncthreads();
    }
    int run = (t == 0) ? 0 : part[t - 1];
    for (int i = lo; i < hi; ++i) { row_ptr[i] = run; run += cnt[i]; }
    if (t == T - 1) row_ptr[N] = E;
}

// ---------------- scatter: group edges by src; write dst_perm and uperm directly ------
__global__ __launch_bounds__(256) void scatter_kernel(
    const int* __restrict__ src, const int* __restrict__ dst,
    const float* __restrict__ u, const int* __restrict__ row_ptr,
    int* __restrict__ dst_perm, float* __restrict__ uperm,
    int N, int E, int NB)
{
    extern __shared__ int curs[];
    const int lo = blockIdx.x * NB;
    const int hi = min(N, lo + NB);
    const int nb = hi - lo;
    if (nb <= 0) return;
    for (int i = threadIdx.x; i < nb; i += blockDim.x) curs[i] = row_ptr[lo + i];
    __syncthreads();
    for (int e = threadIdx.x; e < E; e += blockDim.x) {
        int s = src[e];
        if (s >= lo && s < hi) {
            int pos = atomicAdd(&curs[s - lo], 1);
            dst_perm[pos] = dst[e];
            uperm[pos] = u[e];
        }
    }
}

// ---------------- init: v0 = dest ? 0 : NEG ----------------
__global__ __launch_bounds__(256) void init_kernel(
    const int* __restrict__ dest_mask, float* __restrict__ v, int N)
{
    int n = blockIdx.x * blockDim.x + threadIdx.x;
    if (n >= N) return;
    v[n] = dest_mask[n] ? 0.0f : NEGV;
}

// ---------------- one value iteration: atomic-free, 8 lanes per node ----------------
__global__ __launch_bounds__(256) void iter_csr_kernel(
    const int* __restrict__ row_ptr, const int* __restrict__ dst_perm,
    const float* __restrict__ uperm, const int* __restrict__ dest_mask,
    const float* __restrict__ cur, float* __restrict__ nxt, int N)
{
    int tid = blockIdx.x * blockDim.x + threadIdx.x;
    int n = tid >> 3;
    int lane8 = tid & 7;
    if (n >= N) return;
    int rs = row_ptr[n];
    int re = row_ptr[n + 1];
    float s = 0.0f;
    for (int j = rs + lane8; j < re; j += 8)
        s += expf(uperm[j] + cur[dst_perm[j]]);
    s += __shfl_xor(s, 4, 8);
    s += __shfl_xor(s, 2, 8);
    s += __shfl_xor(s, 1, 8);
    if (lane8 == 0)
        nxt[n] = dest_mask[n] ? 0.0f : (s > 0.0f ? logf(s) : NEGV);
}

// ---------------- prob = exp((u + v[dst]) - v[src]) ----------------
__global__ __launch_bounds__(256) void prob_kernel(
    const float* __restrict__ u, const int* __restrict__ src,
    const int* __restrict__ dst, const float* __restrict__ v,
    float* __restrict__ prob, int E)
{
    int e = blockIdx.x * blockDim.x + threadIdx.x;
    if (e >= E) return;
    prob[e] = expf((u[e] + v[dst[e]]) - v[src[e]]);
}

// ================= fallback (atomic multi-launch path, no workspace needed) ==========
__global__ __launch_bounds__(256) void init_pass(
    const int* __restrict__ dest_mask, float* v, float* s, int N)
{
    int n = blockIdx.x * blockDim.x + threadIdx.x;
    if (n >= N) return;
    v[n] = dest_mask[n] ? 0.0f : NEGV;
    s[n] = 0.0f;
}
__global__ __launch_bounds__(256) void edge_pass(
    const float* __restrict__ u, const int* __restrict__ src,
    const int* __restrict__ dst, const float* __restrict__ v, float* s, int E)
{
    int e = blockIdx.x * blockDim.x + threadIdx.x;
    if (e >= E) return;
    atomicAdd(&s[src[e]], expf(u[e] + v[dst[e]]));
}
__global__ __launch_bounds__(256) void node_pass(
    const int* __restrict__ dest_mask, float* v, float* s, int N)
{
    int n = blockIdx.x * blockDim.x + threadIdx.x;
    if (n >= N) return;
    float sv = s[n];
    v[n] = dest_mask[n] ? 0.0f : (sv > 0.0f ? logf(sv) : NEGV);
    s[n] = 0.0f;
}

// ---------------- host ----------------
extern "C" void kernel_launch(void* const* d_in, const int* in_sizes, int n_in,
                              void* d_out, int out_size, void* d_ws, size_t ws_size,
                              hipStream_t stream)
{
    const float* feats     = (const float*)d_in[0];
    const int*   dest_mask = (const int*)d_in[1];   // bool canonicalized to int32
    const int*   edge_index= (const int*)d_in[2];
    const float* weight    = (const float*)d_in[5];
    const float* bias      = (const float*)d_in[6];

    const int F = in_sizes[5];
    const int E = in_sizes[2] / 2;
    const int N = in_sizes[1];

    const int* src = edge_index;       // row 0
    const int* dst = edge_index + E;   // row 1

    float* out   = (float*)d_out;
    float* value = out;
    float* util  = out + N;
    float* prob  = out + (size_t)N + (size_t)E;

    const int eb = (E + 255) / 256;
    const int nb = (N + 255) / 256;

    // K1: util / u
    util_kernel<<<eb, 256, 0, stream>>>(feats, weight, bias, util, E, F);

    // workspace layout for CSR path: row_ptr(N+1) cnt(N) dst_perm(E) uperm(E) va(N) vb(N)
    const size_t need_bytes = ((size_t)2 * E + 4 * (size_t)N + 1) * 4;

    if (d_ws != nullptr && ws_size >= need_bytes) {
        int*   row_ptr = (int*)d_ws;
        int*   cnt     = row_ptr + (N + 1);
        int*   dstp    = cnt + N;
        float* uperm   = (float*)(dstp + E);
        float* va      = uperm + E;
        float* vb      = va + N;

        const int NB = (N + HIST_BLOCKS - 1) / HIST_BLOCKS;
        const size_t lds_bytes = (size_t)NB * 4;

        hist_kernel<<<HIST_BLOCKS, 256, lds_bytes, stream>>>(src, cnt, N, E, NB);
        scan_kernel<<<1, 1024, 0, stream>>>(cnt, row_ptr, N, E);
        scatter_kernel<<<HIST_BLOCKS, 256, lds_bytes, stream>>>(
            src, dst, util, row_ptr, dstp, uperm, N, E, NB);

        init_kernel<<<nb, 256, 0, stream>>>(dest_mask, va, N);

        const int gb = ((N * 8) + 255) / 256;  // 8 lanes per node
        float* cur = va;
        float* nxt = vb;
        for (int it = 0; it < N_ITERS; ++it) {
            float* dst_buf = (it == N_ITERS - 1) ? value : nxt;
            iter_csr_kernel<<<gb, 256, 0, stream>>>(
                row_ptr, dstp, uperm, dest_mask, cur, dst_buf, N);
            float* t = cur; cur = nxt; nxt = t;
        }
        // final v is in `value`
        prob_kernel<<<eb, 256, 0, stream>>>(util, src, dst, value, prob, E);
    } else {
        // fallback: atomic multi-launch path; s carved from prob region (overwritten at end)
        float* s = prob;
        init_pass<<<nb, 256, 0, stream>>>(dest_mask, value, s, N);
        for (int it = 0; it < N_ITERS; ++it) {
            edge_pass<<<eb, 256, 0, stream>>>(util, src, dst, value, s, E);
            node_pass<<<nb, 256, 0, stream>>>(dest_mask, value, s, N);
        }
        prob_kernel<<<eb, 256, 0, stream>>>(util, src, dst, value, prob, E);
    }
}

// Round 5
// 838.104 us; speedup vs baseline: 38.1149x; 6.5637x over previous
//
#include <hip/hip_runtime.h>

#define NEGV (-1000000000.0f)
#define N_ITERS 32
#define NBUCK 512
#define B1 256
#define CAP 12288

// ---------------- util: u[e] = clip(dot(feats[e], w) + b, -100, -1e-6) ----------------
__global__ __launch_bounds__(256) void util_kernel(
    const float* __restrict__ feats, const float* __restrict__ weight,
    const float* __restrict__ bias, float* __restrict__ u,
    int E, int F)
{
    int e = blockIdx.x * blockDim.x + threadIdx.x;
    if (e >= E) return;
    const float* row = feats + (size_t)e * (size_t)F;
    float acc = 0.0f;
    for (int f = 0; f < F; f += 4) {
        float4 fv = *reinterpret_cast<const float4*>(row + f);
        acc += fv.x * weight[f + 0];
        acc += fv.y * weight[f + 1];
        acc += fv.z * weight[f + 2];
        acc += fv.w * weight[f + 3];
    }
    acc += bias[0];
    acc = fminf(fmaxf(acc, -100.0f), -1e-6f);
    u[e] = acc;
}

// ---------------- pass 1: per-block coarse-bucket histogram (LDS, no global atomics) ---
__global__ __launch_bounds__(256) void bucket_count(
    const int* __restrict__ src, int* __restrict__ hists,
    int E, int W, int chunk)
{
    __shared__ int h[NBUCK];
    for (int i = threadIdx.x; i < NBUCK; i += 256) h[i] = 0;
    __syncthreads();
    const int lo = blockIdx.x * chunk;
    const int hi = min(E, lo + chunk);
    for (int e = lo + threadIdx.x; e < hi; e += 256) {
        unsigned k = (unsigned)src[e] / (unsigned)W;
        atomicAdd(&h[k], 1);
    }
    __syncthreads();
    for (int i = threadIdx.x; i < NBUCK; i += 256)
        hists[blockIdx.x * NBUCK + i] = h[i];
}

// ---------------- pass 2: scan — per-block offsets + bucket starts (coalesced) --------
__global__ __launch_bounds__(NBUCK) void bucket_scan(
    int* __restrict__ hists, int* __restrict__ bstarts, int E)
{
    __shared__ int tot[NBUCK];
    __shared__ int sc[NBUCK];
    const int k = threadIdx.x;
    int sum = 0;
    for (int b = 0; b < B1; ++b) sum += hists[b * NBUCK + k]; // coalesced rows
    tot[k] = sum;
    sc[k] = sum;
    __syncthreads();
    for (int off = 1; off < NBUCK; off <<= 1) {
        int v = sc[k];
        if (k >= off) v += sc[k - off];
        __syncthreads();
        sc[k] = v;
        __syncthreads();
    }
    const int start = sc[k] - tot[k];   // exclusive prefix
    bstarts[k] = start;
    if (k == NBUCK - 1) bstarts[NBUCK] = E;
    int run = start;
    for (int b = 0; b < B1; ++b) {      // coalesced rows
        int c = hists[b * NBUCK + k];
        hists[b * NBUCK + k] = run;
        run += c;
    }
}

// ---------------- pass 3: scatter edges into coarse-bucket regions --------------------
// pk[pos] = (src_local << 20) | dst ; ub[pos] = u[e]
__global__ __launch_bounds__(256) void bucket_scatter(
    const int* __restrict__ src, const int* __restrict__ dst,
    const float* __restrict__ u, const int* __restrict__ hists,
    int* __restrict__ pk, float* __restrict__ ub,
    int E, int W, int chunk)
{
    __shared__ int cur[NBUCK];
    for (int i = threadIdx.x; i < NBUCK; i += 256)
        cur[i] = hists[blockIdx.x * NBUCK + i];
    __syncthreads();
    const int lo = blockIdx.x * chunk;
    const int hi = min(E, lo + chunk);
    for (int e = lo + threadIdx.x; e < hi; e += 256) {
        int s = src[e];
        unsigned k = (unsigned)s / (unsigned)W;
        int pos = atomicAdd(&cur[k], 1);
        unsigned sl = (unsigned)s - k * (unsigned)W;
        pk[pos] = (int)((sl << 20) | (unsigned)dst[e]);
        ub[pos] = u[e];
    }
}

// ---------------- pass 4: fine sort within bucket (LDS-staged, in-place) --------------
// Produces final CSR: pk -> dst_perm, ub -> uperm, plus row_ptr.
__global__ __launch_bounds__(256) void fine_sort(
    const int* __restrict__ bstarts, int* __restrict__ pk, float* __restrict__ ub,
    int* __restrict__ row_ptr, int N, int E, int W)
{
    extern __shared__ int smem[];
    int*   pks = smem;                  // CAP
    float* ubs = (float*)(smem + CAP);  // CAP
    int*   fh  = smem + 2 * CAP;        // W counters/cursors

    const int k  = blockIdx.x;
    const int lo = k * W;
    const int nn = min(N, lo + W) - lo;
    if (k == 0 && threadIdx.x == 0) row_ptr[N] = E;
    if (nn <= 0) return;

    const int bs  = bstarts[k];
    const int be  = bstarts[k + 1];
    const int cnt = be - bs;

    int ldcnt = min(cnt, CAP);          // cnt <= CAP for this input (guarded by stats)
    for (int i = threadIdx.x; i < ldcnt; i += blockDim.x) {
        pks[i] = pk[bs + i];
        ubs[i] = ub[bs + i];
    }
    for (int i = threadIdx.x; i < nn; i += blockDim.x) fh[i] = 0;
    __syncthreads();

    for (int i = threadIdx.x; i < ldcnt; i += blockDim.x)
        atomicAdd(&fh[((unsigned)pks[i]) >> 20], 1);
    __syncthreads();

    if (threadIdx.x == 0) {
        int run = bs;
        for (int i = 0; i < nn; ++i) {
            int c = fh[i];
            fh[i] = run;                // cursor start
            row_ptr[lo + i] = run;
            run += c;
        }
    }
    __syncthreads();

    for (int i = threadIdx.x; i < ldcnt; i += blockDim.x) {
        int w = pks[i];
        int pos = atomicAdd(&fh[((unsigned)w) >> 20], 1);
        pk[pos] = w & 0xFFFFF;          // final dst_perm
        ub[pos] = ubs[i];               // final uperm
    }
}

// ---------------- init: v0 = dest ? 0 : NEG ----------------
__global__ __launch_bounds__(256) void init_kernel(
    const int* __restrict__ dest_mask, float* __restrict__ v, int N)
{
    int n = blockIdx.x * blockDim.x + threadIdx.x;
    if (n >= N) return;
    v[n] = dest_mask[n] ? 0.0f : NEGV;
}

// ---------------- one value iteration: atomic-free, 8 lanes per node ----------------
__global__ __launch_bounds__(256) void iter_csr_kernel(
    const int* __restrict__ row_ptr, const int* __restrict__ dst_perm,
    const float* __restrict__ uperm, const int* __restrict__ dest_mask,
    const float* __restrict__ cur, float* __restrict__ nxt, int N)
{
    int tid = blockIdx.x * blockDim.x + threadIdx.x;
    int n = tid >> 3;
    int lane8 = tid & 7;
    if (n >= N) return;
    int rs = row_ptr[n];
    int re = row_ptr[n + 1];
    float s = 0.0f;
    for (int j = rs + lane8; j < re; j += 8)
        s += expf(uperm[j] + cur[dst_perm[j]]);
    s += __shfl_xor(s, 4, 8);
    s += __shfl_xor(s, 2, 8);
    s += __shfl_xor(s, 1, 8);
    if (lane8 == 0)
        nxt[n] = dest_mask[n] ? 0.0f : (s > 0.0f ? logf(s) : NEGV);
}

// ---------------- prob = exp((u + v[dst]) - v[src]) ----------------
__global__ __launch_bounds__(256) void prob_kernel(
    const float* __restrict__ u, const int* __restrict__ src,
    const int* __restrict__ dst, const float* __restrict__ v,
    float* __restrict__ prob, int E)
{
    int e = blockIdx.x * blockDim.x + threadIdx.x;
    if (e >= E) return;
    prob[e] = expf((u[e] + v[dst[e]]) - v[src[e]]);
}

// ================= zero-workspace fallback (atomic multi-launch path) ================
__global__ __launch_bounds__(256) void init_pass(
    const int* __restrict__ dest_mask, float* v, float* s, int N)
{
    int n = blockIdx.x * blockDim.x + threadIdx.x;
    if (n >= N) return;
    v[n] = dest_mask[n] ? 0.0f : NEGV;
    s[n] = 0.0f;
}
__global__ __launch_bounds__(256) void edge_pass(
    const float* __restrict__ u, const int* __restrict__ src,
    const int* __restrict__ dst, const float* __restrict__ v, float* s, int E)
{
    int e = blockIdx.x * blockDim.x + threadIdx.x;
    if (e >= E) return;
    atomicAdd(&s[src[e]], expf(u[e] + v[dst[e]]));
}
__global__ __launch_bounds__(256) void node_pass(
    const int* __restrict__ dest_mask, float* v, float* s, int N)
{
    int n = blockIdx.x * blockDim.x + threadIdx.x;
    if (n >= N) return;
    float sv = s[n];
    v[n] = dest_mask[n] ? 0.0f : (sv > 0.0f ? logf(sv) : NEGV);
    s[n] = 0.0f;
}

// ---------------- host ----------------
extern "C" void kernel_launch(void* const* d_in, const int* in_sizes, int n_in,
                              void* d_out, int out_size, void* d_ws, size_t ws_size,
                              hipStream_t stream)
{
    const float* feats     = (const float*)d_in[0];
    const int*   dest_mask = (const int*)d_in[1];   // bool canonicalized to int32
    const int*   edge_index= (const int*)d_in[2];
    const float* weight    = (const float*)d_in[5];
    const float* bias      = (const float*)d_in[6];

    const int F = in_sizes[5];
    const int E = in_sizes[2] / 2;
    const int N = in_sizes[1];

    const int* src = edge_index;       // row 0
    const int* dst = edge_index + E;   // row 1

    float* out   = (float*)d_out;
    float* value = out;
    float* util  = out + N;
    float* prob  = out + (size_t)N + (size_t)E;

    const int eb = (E + 255) / 256;
    const int nb = (N + 255) / 256;

    // K1: util / u
    util_kernel<<<eb, 256, 0, stream>>>(feats, weight, bias, util, E, F);

    const int W = (N + NBUCK - 1) / NBUCK;          // nodes per bucket

    // ws layout: hists(B1*NBUCK) bstarts(NBUCK+1) pk(E) ub(E) row_ptr(N+1) va(N) vb(N)
    const size_t need_words = (size_t)B1 * NBUCK + (NBUCK + 1)
                            + 2 * (size_t)E + 3 * (size_t)N + 1;
    const size_t need_bytes = need_words * 4;

    const bool pack_ok = (N < (1 << 20)) && (W <= (1 << 12));

    if (d_ws != nullptr && ws_size >= need_bytes && pack_ok) {
        int*   hists   = (int*)d_ws;
        int*   bstarts = hists + (size_t)B1 * NBUCK;
        int*   pk      = bstarts + (NBUCK + 1);
        float* ub      = (float*)(pk + E);
        int*   row_ptr = (int*)(ub + E);
        float* va      = (float*)(row_ptr + (N + 1));
        float* vb      = va + N;

        const int chunk = (E + B1 - 1) / B1;
        const size_t fine_lds = (size_t)(2 * CAP + W + 8) * 4;

        bucket_count  <<<B1, 256, 0, stream>>>(src, hists, E, W, chunk);
        bucket_scan   <<<1, NBUCK, 0, stream>>>(hists, bstarts, E);
        bucket_scatter<<<B1, 256, 0, stream>>>(src, dst, util, hists, pk, ub, E, W, chunk);
        fine_sort     <<<NBUCK, 256, fine_lds, stream>>>(bstarts, pk, ub, row_ptr, N, E, W);

        init_kernel<<<nb, 256, 0, stream>>>(dest_mask, va, N);

        const int gb = ((N * 8) + 255) / 256;  // 8 lanes per node
        float* cur = va;
        float* nxt = vb;
        for (int it = 0; it < N_ITERS; ++it) {
            float* dst_buf = (it == N_ITERS - 1) ? value : nxt;
            iter_csr_kernel<<<gb, 256, 0, stream>>>(
                row_ptr, pk, ub, dest_mask, cur, dst_buf, N);
            float* t = cur; cur = nxt; nxt = t;
        }
        prob_kernel<<<eb, 256, 0, stream>>>(util, src, dst, value, prob, E);
    } else {
        // fallback: atomic multi-launch path; s carved from prob region
        float* s = prob;
        init_pass<<<nb, 256, 0, stream>>>(dest_mask, value, s, N);
        for (int it = 0; it < N_ITERS; ++it) {
            edge_pass<<<eb, 256, 0, stream>>>(util, src, dst, value, s, E);
            node_pass<<<nb, 256, 0, stream>>>(dest_mask, value, s, N);
        }
        prob_kernel<<<eb, 256, 0, stream>>>(util, src, dst, value, prob, E);
    }
}

// Round 6
// 543.370 us; speedup vs baseline: 58.7892x; 1.5424x over previous
//
#include <hip/hip_runtime.h>

#define NEGV (-1000000000.0f)
#define N_ITERS 32
#define NBUCK 512
#define B1 256
#define CAP 12288

// ---------------- util (F==64 fast path): 16 lanes per row, fully coalesced ----------
// u[e] = clip(dot(feats[e], w) + b, -100, -1e-6)
__global__ __launch_bounds__(256) void util_kernel64(
    const float* __restrict__ feats, const float* __restrict__ weight,
    const float* __restrict__ bias, float* __restrict__ u, int E)
{
    int tid = blockIdx.x * blockDim.x + threadIdx.x;
    int e = tid >> 4;        // row index
    int l = tid & 15;        // lane-in-row
    if (e >= E) return;
    float4 fv = *reinterpret_cast<const float4*>(feats + (size_t)e * 64 + l * 4);
    float4 wv = *reinterpret_cast<const float4*>(weight + l * 4);
    float acc = fv.x * wv.x + fv.y * wv.y + fv.z * wv.z + fv.w * wv.w;
    acc += __shfl_xor(acc, 8, 16);
    acc += __shfl_xor(acc, 4, 16);
    acc += __shfl_xor(acc, 2, 16);
    acc += __shfl_xor(acc, 1, 16);
    if (l == 0) {
        acc += bias[0];
        u[e] = fminf(fmaxf(acc, -100.0f), -1e-6f);
    }
}

// ---------------- util generic fallback (any F % 4 == 0) ----------------
__global__ __launch_bounds__(256) void util_kernel(
    const float* __restrict__ feats, const float* __restrict__ weight,
    const float* __restrict__ bias, float* __restrict__ u,
    int E, int F)
{
    int e = blockIdx.x * blockDim.x + threadIdx.x;
    if (e >= E) return;
    const float* row = feats + (size_t)e * (size_t)F;
    float acc = 0.0f;
    for (int f = 0; f < F; f += 4) {
        float4 fv = *reinterpret_cast<const float4*>(row + f);
        acc += fv.x * weight[f + 0];
        acc += fv.y * weight[f + 1];
        acc += fv.z * weight[f + 2];
        acc += fv.w * weight[f + 3];
    }
    acc += bias[0];
    acc = fminf(fmaxf(acc, -100.0f), -1e-6f);
    u[e] = acc;
}

// ---------------- pass 1: per-block coarse-bucket histogram (LDS) ----------------
__global__ __launch_bounds__(256) void bucket_count(
    const int* __restrict__ src, int* __restrict__ hists,
    int E, int W, int chunk)
{
    __shared__ int h[NBUCK];
    for (int i = threadIdx.x; i < NBUCK; i += 256) h[i] = 0;
    __syncthreads();
    const int lo = blockIdx.x * chunk;
    const int hi = min(E, lo + chunk);
    for (int e = lo + threadIdx.x; e < hi; e += 256) {
        unsigned k = (unsigned)src[e] / (unsigned)W;
        atomicAdd(&h[k], 1);
    }
    __syncthreads();
    for (int i = threadIdx.x; i < NBUCK; i += 256)
        hists[blockIdx.x * NBUCK + i] = h[i];
}

// ---------------- pass 2: scan — per-block offsets + bucket starts ----------------
__global__ __launch_bounds__(NBUCK) void bucket_scan(
    int* __restrict__ hists, int* __restrict__ bstarts, int E)
{
    __shared__ int tot[NBUCK];
    __shared__ int sc[NBUCK];
    const int k = threadIdx.x;
    int sum = 0;
    for (int b = 0; b < B1; ++b) sum += hists[b * NBUCK + k];
    tot[k] = sum;
    sc[k] = sum;
    __syncthreads();
    for (int off = 1; off < NBUCK; off <<= 1) {
        int v = sc[k];
        if (k >= off) v += sc[k - off];
        __syncthreads();
        sc[k] = v;
        __syncthreads();
    }
    const int start = sc[k] - tot[k];
    bstarts[k] = start;
    if (k == NBUCK - 1) bstarts[NBUCK] = E;
    int run = start;
    for (int b = 0; b < B1; ++b) {
        int c = hists[b * NBUCK + k];
        hists[b * NBUCK + k] = run;
        run += c;
    }
}

// ---------------- pass 3: scatter edges into coarse-bucket regions --------------------
__global__ __launch_bounds__(256) void bucket_scatter(
    const int* __restrict__ src, const int* __restrict__ dst,
    const float* __restrict__ u, const int* __restrict__ hists,
    int* __restrict__ pk, float* __restrict__ ub,
    int E, int W, int chunk)
{
    __shared__ int cur[NBUCK];
    for (int i = threadIdx.x; i < NBUCK; i += 256)
        cur[i] = hists[blockIdx.x * NBUCK + i];
    __syncthreads();
    const int lo = blockIdx.x * chunk;
    const int hi = min(E, lo + chunk);
    for (int e = lo + threadIdx.x; e < hi; e += 256) {
        int s = src[e];
        unsigned k = (unsigned)s / (unsigned)W;
        int pos = atomicAdd(&cur[k], 1);
        unsigned sl = (unsigned)s - k * (unsigned)W;
        pk[pos] = (int)((sl << 20) | (unsigned)dst[e]);
        ub[pos] = u[e];
    }
}

// ---------------- pass 4: fine sort within bucket (LDS-staged, in-place) --------------
__global__ __launch_bounds__(256) void fine_sort(
    const int* __restrict__ bstarts, int* __restrict__ pk, float* __restrict__ ub,
    int* __restrict__ row_ptr, int N, int E, int W)
{
    extern __shared__ int smem[];
    int*   pks = smem;
    float* ubs = (float*)(smem + CAP);
    int*   fh  = smem + 2 * CAP;

    const int k  = blockIdx.x;
    const int lo = k * W;
    const int nn = min(N, lo + W) - lo;
    if (k == 0 && threadIdx.x == 0) row_ptr[N] = E;
    if (nn <= 0) return;

    const int bs  = bstarts[k];
    const int be  = bstarts[k + 1];
    const int cnt = be - bs;

    int ldcnt = min(cnt, CAP);
    for (int i = threadIdx.x; i < ldcnt; i += blockDim.x) {
        pks[i] = pk[bs + i];
        ubs[i] = ub[bs + i];
    }
    for (int i = threadIdx.x; i < nn; i += blockDim.x) fh[i] = 0;
    __syncthreads();

    for (int i = threadIdx.x; i < ldcnt; i += blockDim.x)
        atomicAdd(&fh[((unsigned)pks[i]) >> 20], 1);
    __syncthreads();

    if (threadIdx.x == 0) {
        int run = bs;
        for (int i = 0; i < nn; ++i) {
            int c = fh[i];
            fh[i] = run;
            row_ptr[lo + i] = run;
            run += c;
        }
    }
    __syncthreads();

    for (int i = threadIdx.x; i < ldcnt; i += blockDim.x) {
        int w = pks[i];
        int pos = atomicAdd(&fh[((unsigned)w) >> 20], 1);
        pk[pos] = w & 0xFFFFF;
        ub[pos] = ubs[i];
    }
}

// ---------------- init: v0 = dest ? 0 : NEG ----------------
__global__ __launch_bounds__(256) void init_kernel(
    const int* __restrict__ dest_mask, float* __restrict__ v, int N)
{
    int n = blockIdx.x * blockDim.x + threadIdx.x;
    if (n >= N) return;
    v[n] = dest_mask[n] ? 0.0f : NEGV;
}

// ---------------- one value iteration: atomic-free, 8 lanes per node ----------------
__global__ __launch_bounds__(256) void iter_csr_kernel(
    const int* __restrict__ row_ptr, const int* __restrict__ dst_perm,
    const float* __restrict__ uperm, const int* __restrict__ dest_mask,
    const float* __restrict__ cur, float* __restrict__ nxt, int N)
{
    int tid = blockIdx.x * blockDim.x + threadIdx.x;
    int n = tid >> 3;
    int lane8 = tid & 7;
    if (n >= N) return;
    int rs = row_ptr[n];
    int re = row_ptr[n + 1];
    float s = 0.0f;
    for (int j = rs + lane8; j < re; j += 8)
        s += expf(uperm[j] + cur[dst_perm[j]]);
    s += __shfl_xor(s, 4, 8);
    s += __shfl_xor(s, 2, 8);
    s += __shfl_xor(s, 1, 8);
    if (lane8 == 0)
        nxt[n] = dest_mask[n] ? 0.0f : (s > 0.0f ? logf(s) : NEGV);
}

// ---------------- prob = exp((u + v[dst]) - v[src]) ----------------
__global__ __launch_bounds__(256) void prob_kernel(
    const float* __restrict__ u, const int* __restrict__ src,
    const int* __restrict__ dst, const float* __restrict__ v,
    float* __restrict__ prob, int E)
{
    int e = blockIdx.x * blockDim.x + threadIdx.x;
    if (e >= E) return;
    prob[e] = expf((u[e] + v[dst[e]]) - v[src[e]]);
}

// ================= zero-workspace fallback (atomic multi-launch path) ================
__global__ __launch_bounds__(256) void init_pass(
    const int* __restrict__ dest_mask, float* v, float* s, int N)
{
    int n = blockIdx.x * blockDim.x + threadIdx.x;
    if (n >= N) return;
    v[n] = dest_mask[n] ? 0.0f : NEGV;
    s[n] = 0.0f;
}
__global__ __launch_bounds__(256) void edge_pass(
    const float* __restrict__ u, const int* __restrict__ src,
    const int* __restrict__ dst, const float* __restrict__ v, float* s, int E)
{
    int e = blockIdx.x * blockDim.x + threadIdx.x;
    if (e >= E) return;
    atomicAdd(&s[src[e]], expf(u[e] + v[dst[e]]));
}
__global__ __launch_bounds__(256) void node_pass(
    const int* __restrict__ dest_mask, float* v, float* s, int N)
{
    int n = blockIdx.x * blockDim.x + threadIdx.x;
    if (n >= N) return;
    float sv = s[n];
    v[n] = dest_mask[n] ? 0.0f : (sv > 0.0f ? logf(sv) : NEGV);
    s[n] = 0.0f;
}

// ---------------- host ----------------
extern "C" void kernel_launch(void* const* d_in, const int* in_sizes, int n_in,
                              void* d_out, int out_size, void* d_ws, size_t ws_size,
                              hipStream_t stream)
{
    const float* feats     = (const float*)d_in[0];
    const int*   dest_mask = (const int*)d_in[1];
    const int*   edge_index= (const int*)d_in[2];
    const float* weight    = (const float*)d_in[5];
    const float* bias      = (const float*)d_in[6];

    const int F = in_sizes[5];
    const int E = in_sizes[2] / 2;
    const int N = in_sizes[1];

    const int* src = edge_index;
    const int* dst = edge_index + E;

    float* out   = (float*)d_out;
    float* value = out;
    float* util  = out + N;
    float* prob  = out + (size_t)N + (size_t)E;

    const int eb = (E + 255) / 256;
    const int nb = (N + 255) / 256;

    // K1: util / u — coalesced 16-lanes-per-row when F==64
    if (F == 64) {
        long long tt = (long long)E * 16;
        int blocks = (int)((tt + 255) / 256);
        util_kernel64<<<blocks, 256, 0, stream>>>(feats, weight, bias, util, E);
    } else {
        util_kernel<<<eb, 256, 0, stream>>>(feats, weight, bias, util, E, F);
    }

    const int W = (N + NBUCK - 1) / NBUCK;

    const size_t need_words = (size_t)B1 * NBUCK + (NBUCK + 1)
                            + 2 * (size_t)E + 3 * (size_t)N + 1;
    const size_t need_bytes = need_words * 4;
    const bool pack_ok = (N < (1 << 20)) && (W <= (1 << 12));

    if (d_ws != nullptr && ws_size >= need_bytes && pack_ok) {
        int*   hists   = (int*)d_ws;
        int*   bstarts = hists + (size_t)B1 * NBUCK;
        int*   pk      = bstarts + (NBUCK + 1);
        float* ub      = (float*)(pk + E);
        int*   row_ptr = (int*)(ub + E);
        float* va      = (float*)(row_ptr + (N + 1));
        float* vb      = va + N;

        const int chunk = (E + B1 - 1) / B1;
        const size_t fine_lds = (size_t)(2 * CAP + W + 8) * 4;

        bucket_count  <<<B1, 256, 0, stream>>>(src, hists, E, W, chunk);
        bucket_scan   <<<1, NBUCK, 0, stream>>>(hists, bstarts, E);
        bucket_scatter<<<B1, 256, 0, stream>>>(src, dst, util, hists, pk, ub, E, W, chunk);
        fine_sort     <<<NBUCK, 256, fine_lds, stream>>>(bstarts, pk, ub, row_ptr, N, E, W);

        init_kernel<<<nb, 256, 0, stream>>>(dest_mask, va, N);

        const int gb = ((N * 8) + 255) / 256;
        float* cur = va;
        float* nxt = vb;
        for (int it = 0; it < N_ITERS; ++it) {
            float* dst_buf = (it == N_ITERS - 1) ? value : nxt;
            iter_csr_kernel<<<gb, 256, 0, stream>>>(
                row_ptr, pk, ub, dest_mask, cur, dst_buf, N);
            float* t = cur; cur = nxt; nxt = t;
        }
        prob_kernel<<<eb, 256, 0, stream>>>(util, src, dst, value, prob, E);
    } else {
        float* s = prob;
        init_pass<<<nb, 256, 0, stream>>>(dest_mask, value, s, N);
        for (int it = 0; it < N_ITERS; ++it) {
            edge_pass<<<eb, 256, 0, stream>>>(util, src, dst, value, s, E);
            node_pass<<<nb, 256, 0, stream>>>(dest_mask, value, s, N);
        }
        prob_kernel<<<eb, 256, 0, stream>>>(util, src, dst, value, prob, E);
    }
}

// Round 7
// 497.745 us; speedup vs baseline: 64.1780x; 1.0917x over previous
//
#include <hip/hip_runtime.h>

#define NEGV (-1000000000.0f)
#define N_ITERS 32
#define NBUCK 512
#define B1 256
#define CAP 12288

// ---------------- util (F==64 fast path): 16 lanes per row, fully coalesced ----------
__global__ __launch_bounds__(256) void util_kernel64(
    const float* __restrict__ feats, const float* __restrict__ weight,
    const float* __restrict__ bias, float* __restrict__ u, int E)
{
    int tid = blockIdx.x * blockDim.x + threadIdx.x;
    int e = tid >> 4;
    int l = tid & 15;
    if (e >= E) return;
    float4 fv = *reinterpret_cast<const float4*>(feats + (size_t)e * 64 + l * 4);
    float4 wv = *reinterpret_cast<const float4*>(weight + l * 4);
    float acc = fv.x * wv.x + fv.y * wv.y + fv.z * wv.z + fv.w * wv.w;
    acc += __shfl_xor(acc, 8, 16);
    acc += __shfl_xor(acc, 4, 16);
    acc += __shfl_xor(acc, 2, 16);
    acc += __shfl_xor(acc, 1, 16);
    if (l == 0) {
        acc += bias[0];
        u[e] = fminf(fmaxf(acc, -100.0f), -1e-6f);
    }
}

// ---------------- util generic fallback ----------------
__global__ __launch_bounds__(256) void util_kernel(
    const float* __restrict__ feats, const float* __restrict__ weight,
    const float* __restrict__ bias, float* __restrict__ u,
    int E, int F)
{
    int e = blockIdx.x * blockDim.x + threadIdx.x;
    if (e >= E) return;
    const float* row = feats + (size_t)e * (size_t)F;
    float acc = 0.0f;
    for (int f = 0; f < F; f += 4) {
        float4 fv = *reinterpret_cast<const float4*>(row + f);
        acc += fv.x * weight[f + 0];
        acc += fv.y * weight[f + 1];
        acc += fv.z * weight[f + 2];
        acc += fv.w * weight[f + 3];
    }
    acc += bias[0];
    acc = fminf(fmaxf(acc, -100.0f), -1e-6f);
    u[e] = acc;
}

// ---------------- pass 1: per-block coarse-bucket histogram (LDS) ----------------
__global__ __launch_bounds__(256) void bucket_count(
    const int* __restrict__ src, int* __restrict__ hists,
    int E, int W, int chunk)
{
    __shared__ int h[NBUCK];
    for (int i = threadIdx.x; i < NBUCK; i += 256) h[i] = 0;
    __syncthreads();
    const int lo = blockIdx.x * chunk;
    const int hi = min(E, lo + chunk);
    for (int e = lo + threadIdx.x; e < hi; e += 256) {
        unsigned k = (unsigned)src[e] / (unsigned)W;
        atomicAdd(&h[k], 1);
    }
    __syncthreads();
    for (int i = threadIdx.x; i < NBUCK; i += 256)
        hists[blockIdx.x * NBUCK + i] = h[i];
}

// ---------------- pass 2: scan — per-block offsets + bucket starts ----------------
__global__ __launch_bounds__(NBUCK) void bucket_scan(
    int* __restrict__ hists, int* __restrict__ bstarts, int E)
{
    __shared__ int tot[NBUCK];
    __shared__ int sc[NBUCK];
    const int k = threadIdx.x;
    int sum = 0;
    for (int b = 0; b < B1; ++b) sum += hists[b * NBUCK + k];
    tot[k] = sum;
    sc[k] = sum;
    __syncthreads();
    for (int off = 1; off < NBUCK; off <<= 1) {
        int v = sc[k];
        if (k >= off) v += sc[k - off];
        __syncthreads();
        sc[k] = v;
        __syncthreads();
    }
    const int start = sc[k] - tot[k];
    bstarts[k] = start;
    if (k == NBUCK - 1) bstarts[NBUCK] = E;
    int run = start;
    for (int b = 0; b < B1; ++b) {
        int c = hists[b * NBUCK + k];
        hists[b * NBUCK + k] = run;
        run += c;
    }
}

// ---------------- pass 3: scatter into coarse buckets; edg = {packed, exp(u) bits} -----
__global__ __launch_bounds__(256) void bucket_scatter(
    const int* __restrict__ src, const int* __restrict__ dst,
    const float* __restrict__ u, const int* __restrict__ hists,
    int2* __restrict__ edg, int E, int W, int chunk)
{
    __shared__ int cur[NBUCK];
    for (int i = threadIdx.x; i < NBUCK; i += 256)
        cur[i] = hists[blockIdx.x * NBUCK + i];
    __syncthreads();
    const int lo = blockIdx.x * chunk;
    const int hi = min(E, lo + chunk);
    for (int e = lo + threadIdx.x; e < hi; e += 256) {
        int s = src[e];
        unsigned k = (unsigned)s / (unsigned)W;
        int pos = atomicAdd(&cur[k], 1);
        unsigned sl = (unsigned)s - k * (unsigned)W;
        int2 rec;
        rec.x = (int)((sl << 20) | (unsigned)dst[e]);
        rec.y = __float_as_int(expf(u[e]));       // one-time exp
        edg[pos] = rec;
    }
}

// ---------------- pass 4: fine sort within bucket (LDS-staged, in-place on edg) -------
// final edg[j] = { dst, exp(u) bits } grouped by src; row_ptr built.
__global__ __launch_bounds__(256) void fine_sort(
    const int* __restrict__ bstarts, int2* __restrict__ edg,
    int* __restrict__ row_ptr, int N, int E, int W)
{
    extern __shared__ int smem[];
    int* pks = smem;            // CAP packed keys
    int* ubs = smem + CAP;      // CAP eu bits
    int* fh  = smem + 2 * CAP;  // W counters/cursors

    const int k  = blockIdx.x;
    const int lo = k * W;
    const int nn = min(N, lo + W) - lo;
    if (k == 0 && threadIdx.x == 0) row_ptr[N] = E;
    if (nn <= 0) return;

    const int bs  = bstarts[k];
    const int be  = bstarts[k + 1];
    const int cnt = be - bs;

    int ldcnt = min(cnt, CAP);
    for (int i = threadIdx.x; i < ldcnt; i += blockDim.x) {
        int2 r = edg[bs + i];
        pks[i] = r.x;
        ubs[i] = r.y;
    }
    for (int i = threadIdx.x; i < nn; i += blockDim.x) fh[i] = 0;
    __syncthreads();

    for (int i = threadIdx.x; i < ldcnt; i += blockDim.x)
        atomicAdd(&fh[((unsigned)pks[i]) >> 20], 1);
    __syncthreads();

    if (threadIdx.x == 0) {
        int run = bs;
        for (int i = 0; i < nn; ++i) {
            int c = fh[i];
            fh[i] = run;
            row_ptr[lo + i] = run;
            run += c;
        }
    }
    __syncthreads();

    for (int i = threadIdx.x; i < ldcnt; i += blockDim.x) {
        int w = pks[i];
        int pos = atomicAdd(&fh[((unsigned)w) >> 20], 1);
        int2 r;
        r.x = w & 0xFFFFF;       // dst
        r.y = ubs[i];            // exp(u) bits
        edg[pos] = r;            // in-place within this block's own range
    }
}

// ---------------- init: ew0 = dest ? 1 : 0 ----------------
__global__ __launch_bounds__(256) void init_exp_kernel(
    const int* __restrict__ dest_mask, float* __restrict__ ew, int N)
{
    int n = blockIdx.x * blockDim.x + threadIdx.x;
    if (n >= N) return;
    ew[n] = dest_mask[n] ? 1.0f : 0.0f;
}

// ---------------- one exp-domain iteration: pure FMA, 8 lanes per node ----------------
__global__ __launch_bounds__(256) void iter_exp_kernel(
    const int* __restrict__ row_ptr, const int2* __restrict__ edg,
    const int* __restrict__ dest_mask,
    const float* __restrict__ ew, float* __restrict__ ew_new, int N)
{
    int tid = blockIdx.x * blockDim.x + threadIdx.x;
    int n = tid >> 3;
    int lane8 = tid & 7;
    if (n >= N) return;
    int rs = row_ptr[n];
    int re = row_ptr[n + 1];
    float s = 0.0f;
    for (int j = rs + lane8; j < re; j += 8) {
        int2 r = edg[j];
        s += __int_as_float(r.y) * ew[r.x];
    }
    s += __shfl_xor(s, 4, 8);
    s += __shfl_xor(s, 2, 8);
    s += __shfl_xor(s, 1, 8);
    if (lane8 == 0)
        ew_new[n] = dest_mask[n] ? 1.0f : s;
}

// ---------------- final iteration: back to log domain ----------------
__global__ __launch_bounds__(256) void final_exp_kernel(
    const int* __restrict__ row_ptr, const int2* __restrict__ edg,
    const int* __restrict__ dest_mask,
    const float* __restrict__ ew, float* __restrict__ value, int N)
{
    int tid = blockIdx.x * blockDim.x + threadIdx.x;
    int n = tid >> 3;
    int lane8 = tid & 7;
    if (n >= N) return;
    int rs = row_ptr[n];
    int re = row_ptr[n + 1];
    float s = 0.0f;
    for (int j = rs + lane8; j < re; j += 8) {
        int2 r = edg[j];
        s += __int_as_float(r.y) * ew[r.x];
    }
    s += __shfl_xor(s, 4, 8);
    s += __shfl_xor(s, 2, 8);
    s += __shfl_xor(s, 1, 8);
    if (lane8 == 0)
        value[n] = dest_mask[n] ? 0.0f : (s > 0.0f ? logf(s) : NEGV);
}

// ---------------- prob = exp((u + v[dst]) - v[src]) ----------------
__global__ __launch_bounds__(256) void prob_kernel(
    const float* __restrict__ u, const int* __restrict__ src,
    const int* __restrict__ dst, const float* __restrict__ v,
    float* __restrict__ prob, int E)
{
    int e = blockIdx.x * blockDim.x + threadIdx.x;
    if (e >= E) return;
    prob[e] = expf((u[e] + v[dst[e]]) - v[src[e]]);
}

// ================= zero-workspace fallback (atomic multi-launch path) ================
__global__ __launch_bounds__(256) void init_pass(
    const int* __restrict__ dest_mask, float* v, float* s, int N)
{
    int n = blockIdx.x * blockDim.x + threadIdx.x;
    if (n >= N) return;
    v[n] = dest_mask[n] ? 0.0f : NEGV;
    s[n] = 0.0f;
}
__global__ __launch_bounds__(256) void edge_pass(
    const float* __restrict__ u, const int* __restrict__ src,
    const int* __restrict__ dst, const float* __restrict__ v, float* s, int E)
{
    int e = blockIdx.x * blockDim.x + threadIdx.x;
    if (e >= E) return;
    atomicAdd(&s[src[e]], expf(u[e] + v[dst[e]]));
}
__global__ __launch_bounds__(256) void node_pass(
    const int* __restrict__ dest_mask, float* v, float* s, int N)
{
    int n = blockIdx.x * blockDim.x + threadIdx.x;
    if (n >= N) return;
    float sv = s[n];
    v[n] = dest_mask[n] ? 0.0f : (sv > 0.0f ? logf(sv) : NEGV);
    s[n] = 0.0f;
}

// ---------------- host ----------------
extern "C" void kernel_launch(void* const* d_in, const int* in_sizes, int n_in,
                              void* d_out, int out_size, void* d_ws, size_t ws_size,
                              hipStream_t stream)
{
    const float* feats     = (const float*)d_in[0];
    const int*   dest_mask = (const int*)d_in[1];
    const int*   edge_index= (const int*)d_in[2];
    const float* weight    = (const float*)d_in[5];
    const float* bias      = (const float*)d_in[6];

    const int F = in_sizes[5];
    const int E = in_sizes[2] / 2;
    const int N = in_sizes[1];

    const int* src = edge_index;
    const int* dst = edge_index + E;

    float* out   = (float*)d_out;
    float* value = out;
    float* util  = out + N;
    float* prob  = out + (size_t)N + (size_t)E;

    const int eb = (E + 255) / 256;
    const int nb = (N + 255) / 256;

    // K1: util / u
    if (F == 64) {
        long long tt = (long long)E * 16;
        int blocks = (int)((tt + 255) / 256);
        util_kernel64<<<blocks, 256, 0, stream>>>(feats, weight, bias, util, E);
    } else {
        util_kernel<<<eb, 256, 0, stream>>>(feats, weight, bias, util, E, F);
    }

    const int W = (N + NBUCK - 1) / NBUCK;

    // ws layout: hists(B1*NBUCK) | bstarts(NBUCK+2, pad->8B align) | edg(int2 E) |
    //            row_ptr(N+1) | ewa(N) | ewb(N)
    const size_t need_words = (size_t)B1 * NBUCK + (NBUCK + 2)
                            + 2 * (size_t)E + 3 * (size_t)N + 1;
    const size_t need_bytes = need_words * 4;
    const bool pack_ok = (N < (1 << 20)) && (W <= (1 << 12));

    if (d_ws != nullptr && ws_size >= need_bytes && pack_ok) {
        int*   hists   = (int*)d_ws;
        int*   bstarts = hists + (size_t)B1 * NBUCK;
        int2*  edg     = (int2*)(bstarts + (NBUCK + 2));   // 8B-aligned
        int*   row_ptr = (int*)(edg + E);
        float* ewa     = (float*)(row_ptr + (N + 1));
        float* ewb     = ewa + N;

        const int chunk = (E + B1 - 1) / B1;
        const size_t fine_lds = (size_t)(2 * CAP + W + 8) * 4;

        bucket_count  <<<B1, 256, 0, stream>>>(src, hists, E, W, chunk);
        bucket_scan   <<<1, NBUCK, 0, stream>>>(hists, bstarts, E);
        bucket_scatter<<<B1, 256, 0, stream>>>(src, dst, util, hists, edg, E, W, chunk);
        fine_sort     <<<NBUCK, 256, fine_lds, stream>>>(bstarts, edg, row_ptr, N, E, W);

        init_exp_kernel<<<nb, 256, 0, stream>>>(dest_mask, ewa, N);

        const int gb = ((N * 8) + 255) / 256;
        float* cur = ewa;
        float* nxt = ewb;
        for (int it = 0; it < N_ITERS - 1; ++it) {
            iter_exp_kernel<<<gb, 256, 0, stream>>>(
                row_ptr, edg, dest_mask, cur, nxt, N);
            float* t = cur; cur = nxt; nxt = t;
        }
        final_exp_kernel<<<gb, 256, 0, stream>>>(
            row_ptr, edg, dest_mask, cur, value, N);

        prob_kernel<<<eb, 256, 0, stream>>>(util, src, dst, value, prob, E);
    } else {
        float* s = prob;
        init_pass<<<nb, 256, 0, stream>>>(dest_mask, value, s, N);
        for (int it = 0; it < N_ITERS; ++it) {
            edge_pass<<<eb, 256, 0, stream>>>(util, src, dst, value, s, E);
            node_pass<<<nb, 256, 0, stream>>>(dest_mask, value, s, N);
        }
        prob_kernel<<<eb, 256, 0, stream>>>(util, src, dst, value, prob, E);
    }
}

// Round 8
// 449.792 us; speedup vs baseline: 71.0201x; 1.1066x over previous
//
#include <hip/hip_runtime.h>

#define NEGV (-1000000000.0f)
#define N_ITERS 32
#define NBUCK 512
#define B1 256
#define CAP 12288

// ---------------- util (F==64 fast path): 16 lanes per row, fully coalesced ----------
__global__ __launch_bounds__(256) void util_kernel64(
    const float* __restrict__ feats, const float* __restrict__ weight,
    const float* __restrict__ bias, float* __restrict__ u, int E)
{
    int tid = blockIdx.x * blockDim.x + threadIdx.x;
    int e = tid >> 4;
    int l = tid & 15;
    if (e >= E) return;
    float4 fv = *reinterpret_cast<const float4*>(feats + (size_t)e * 64 + l * 4);
    float4 wv = *reinterpret_cast<const float4*>(weight + l * 4);
    float acc = fv.x * wv.x + fv.y * wv.y + fv.z * wv.z + fv.w * wv.w;
    acc += __shfl_xor(acc, 8, 16);
    acc += __shfl_xor(acc, 4, 16);
    acc += __shfl_xor(acc, 2, 16);
    acc += __shfl_xor(acc, 1, 16);
    if (l == 0) {
        acc += bias[0];
        u[e] = fminf(fmaxf(acc, -100.0f), -1e-6f);
    }
}

// ---------------- util generic fallback ----------------
__global__ __launch_bounds__(256) void util_kernel(
    const float* __restrict__ feats, const float* __restrict__ weight,
    const float* __restrict__ bias, float* __restrict__ u,
    int E, int F)
{
    int e = blockIdx.x * blockDim.x + threadIdx.x;
    if (e >= E) return;
    const float* row = feats + (size_t)e * (size_t)F;
    float acc = 0.0f;
    for (int f = 0; f < F; f += 4) {
        float4 fv = *reinterpret_cast<const float4*>(row + f);
        acc += fv.x * weight[f + 0];
        acc += fv.y * weight[f + 1];
        acc += fv.z * weight[f + 2];
        acc += fv.w * weight[f + 3];
    }
    acc += bias[0];
    acc = fminf(fmaxf(acc, -100.0f), -1e-6f);
    u[e] = acc;
}

// ---------------- pass 1: per-block coarse-bucket histogram (LDS) ----------------
__global__ __launch_bounds__(256) void bucket_count(
    const int* __restrict__ src, int* __restrict__ hists,
    int E, int W, int chunk)
{
    __shared__ int h[NBUCK];
    for (int i = threadIdx.x; i < NBUCK; i += 256) h[i] = 0;
    __syncthreads();
    const int lo = blockIdx.x * chunk;
    const int hi = min(E, lo + chunk);
    for (int e = lo + threadIdx.x; e < hi; e += 256) {
        unsigned k = (unsigned)src[e] / (unsigned)W;
        atomicAdd(&h[k], 1);
    }
    __syncthreads();
    for (int i = threadIdx.x; i < NBUCK; i += 256)
        hists[blockIdx.x * NBUCK + i] = h[i];
}

// ---------------- pass 2: scan — per-block offsets + bucket starts ----------------
__global__ __launch_bounds__(NBUCK) void bucket_scan(
    int* __restrict__ hists, int* __restrict__ bstarts, int E)
{
    __shared__ int tot[NBUCK];
    __shared__ int sc[NBUCK];
    const int k = threadIdx.x;
    int sum = 0;
    for (int b = 0; b < B1; ++b) sum += hists[b * NBUCK + k];
    tot[k] = sum;
    sc[k] = sum;
    __syncthreads();
    for (int off = 1; off < NBUCK; off <<= 1) {
        int v = sc[k];
        if (k >= off) v += sc[k - off];
        __syncthreads();
        sc[k] = v;
        __syncthreads();
    }
    const int start = sc[k] - tot[k];
    bstarts[k] = start;
    if (k == NBUCK - 1) bstarts[NBUCK] = E;
    int run = start;
    for (int b = 0; b < B1; ++b) {
        int c = hists[b * NBUCK + k];
        hists[b * NBUCK + k] = run;
        run += c;
    }
}

// ---------------- pass 3: scatter into coarse buckets; edg = {packed, exp(u) bits} -----
__global__ __launch_bounds__(256) void bucket_scatter(
    const int* __restrict__ src, const int* __restrict__ dst,
    const float* __restrict__ u, const int* __restrict__ hists,
    int2* __restrict__ edg, int E, int W, int chunk)
{
    __shared__ int cur[NBUCK];
    for (int i = threadIdx.x; i < NBUCK; i += 256)
        cur[i] = hists[blockIdx.x * NBUCK + i];
    __syncthreads();
    const int lo = blockIdx.x * chunk;
    const int hi = min(E, lo + chunk);
    for (int e = lo + threadIdx.x; e < hi; e += 256) {
        int s = src[e];
        unsigned k = (unsigned)s / (unsigned)W;
        int pos = atomicAdd(&cur[k], 1);
        unsigned sl = (unsigned)s - k * (unsigned)W;
        int2 rec;
        rec.x = (int)((sl << 20) | (unsigned)dst[e]);
        rec.y = __float_as_int(expf(u[e]));       // one-time exp
        edg[pos] = rec;
    }
}

// ---------------- pass 4: fine sort within bucket (LDS-staged, in-place on edg) -------
__global__ __launch_bounds__(256) void fine_sort(
    const int* __restrict__ bstarts, int2* __restrict__ edg,
    int* __restrict__ row_ptr, int N, int E, int W)
{
    extern __shared__ int smem[];
    int* pks = smem;            // CAP packed keys
    int* ubs = smem + CAP;      // CAP eu bits
    int* fh  = smem + 2 * CAP;  // W counters/cursors

    const int k  = blockIdx.x;
    const int lo = k * W;
    const int nn = min(N, lo + W) - lo;
    if (k == 0 && threadIdx.x == 0) row_ptr[N] = E;
    if (nn <= 0) return;

    const int bs  = bstarts[k];
    const int be  = bstarts[k + 1];
    const int cnt = be - bs;

    int ldcnt = min(cnt, CAP);
    for (int i = threadIdx.x; i < ldcnt; i += blockDim.x) {
        int2 r = edg[bs + i];
        pks[i] = r.x;
        ubs[i] = r.y;
    }
    for (int i = threadIdx.x; i < nn; i += blockDim.x) fh[i] = 0;
    __syncthreads();

    for (int i = threadIdx.x; i < ldcnt; i += blockDim.x)
        atomicAdd(&fh[((unsigned)pks[i]) >> 20], 1);
    __syncthreads();

    if (threadIdx.x == 0) {
        int run = bs;
        for (int i = 0; i < nn; ++i) {
            int c = fh[i];
            fh[i] = run;
            row_ptr[lo + i] = run;
            run += c;
        }
    }
    __syncthreads();

    for (int i = threadIdx.x; i < ldcnt; i += blockDim.x) {
        int w = pks[i];
        int pos = atomicAdd(&fh[((unsigned)w) >> 20], 1);
        int2 r;
        r.x = w & 0xFFFFF;
        r.y = ubs[i];
        edg[pos] = r;
    }
}

// ---------------- init: ew0 = dest ? 1 : 0 ; flags[0]=1, flags[1..]=0 ----------------
__global__ __launch_bounds__(256) void init_exp_kernel(
    const int* __restrict__ dest_mask, float* __restrict__ ew,
    int* __restrict__ flags, int N)
{
    int n = blockIdx.x * blockDim.x + threadIdx.x;
    if (blockIdx.x == 0 && threadIdx.x <= N_ITERS)
        flags[threadIdx.x] = (threadIdx.x == 0) ? 1 : 0;
    if (n >= N) return;
    ew[n] = dest_mask[n] ? 1.0f : 0.0f;
}

// ---------------- one exp-domain iteration with convergence gating ----------------
// If previous iteration changed nothing (fixed point), degrade to coalesced copy.
__global__ __launch_bounds__(256) void iter_exp_conv(
    const int* __restrict__ row_ptr, const int2* __restrict__ edg,
    const int* __restrict__ dest_mask,
    const float* __restrict__ ew, float* __restrict__ ew_new,
    const int* __restrict__ flag_prev, int* __restrict__ flag_cur, int N)
{
    __shared__ int blk_changed;
    int tid = blockIdx.x * blockDim.x + threadIdx.x;

    if (*flag_prev == 0) {
        // converged: pure coalesced copy, one element per thread
        if (tid < N) ew_new[tid] = ew[tid];
        return;
    }

    if (threadIdx.x == 0) blk_changed = 0;
    __syncthreads();

    int n = tid >> 3;
    int lane8 = tid & 7;
    if (n < N) {
        int rs = row_ptr[n];
        int re = row_ptr[n + 1];
        float s = 0.0f;
        for (int j = rs + lane8; j < re; j += 8) {
            int2 r = edg[j];
            s += __int_as_float(r.y) * ew[r.x];
        }
        s += __shfl_xor(s, 4, 8);
        s += __shfl_xor(s, 2, 8);
        s += __shfl_xor(s, 1, 8);
        if (lane8 == 0) {
            float nv = dest_mask[n] ? 1.0f : s;
            ew_new[n] = nv;
            if (nv != ew[n]) blk_changed = 1;   // benign race: all write 1
        }
    }
    __syncthreads();
    if (threadIdx.x == 0 && blk_changed) atomicOr(flag_cur, 1);
}

// ---------------- final: one more iteration then back to log domain ----------------
__global__ __launch_bounds__(256) void final_exp_conv(
    const int* __restrict__ row_ptr, const int2* __restrict__ edg,
    const int* __restrict__ dest_mask,
    const float* __restrict__ ew, float* __restrict__ value,
    const int* __restrict__ flag_prev, int N)
{
    int tid = blockIdx.x * blockDim.x + threadIdx.x;

    if (*flag_prev == 0) {
        // converged: value = log(ew) directly
        if (tid < N) {
            float s = ew[tid];
            value[tid] = dest_mask[tid] ? 0.0f : (s > 0.0f ? logf(s) : NEGV);
        }
        return;
    }

    int n = tid >> 3;
    int lane8 = tid & 7;
    if (n >= N) return;
    int rs = row_ptr[n];
    int re = row_ptr[n + 1];
    float s = 0.0f;
    for (int j = rs + lane8; j < re; j += 8) {
        int2 r = edg[j];
        s += __int_as_float(r.y) * ew[r.x];
    }
    s += __shfl_xor(s, 4, 8);
    s += __shfl_xor(s, 2, 8);
    s += __shfl_xor(s, 1, 8);
    if (lane8 == 0)
        value[n] = dest_mask[n] ? 0.0f : (s > 0.0f ? logf(s) : NEGV);
}

// ---------------- prob = exp((u + v[dst]) - v[src]) ----------------
__global__ __launch_bounds__(256) void prob_kernel(
    const float* __restrict__ u, const int* __restrict__ src,
    const int* __restrict__ dst, const float* __restrict__ v,
    float* __restrict__ prob, int E)
{
    int e = blockIdx.x * blockDim.x + threadIdx.x;
    if (e >= E) return;
    prob[e] = expf((u[e] + v[dst[e]]) - v[src[e]]);
}

// ================= zero-workspace fallback (atomic multi-launch path) ================
__global__ __launch_bounds__(256) void init_pass(
    const int* __restrict__ dest_mask, float* v, float* s, int N)
{
    int n = blockIdx.x * blockDim.x + threadIdx.x;
    if (n >= N) return;
    v[n] = dest_mask[n] ? 0.0f : NEGV;
    s[n] = 0.0f;
}
__global__ __launch_bounds__(256) void edge_pass(
    const float* __restrict__ u, const int* __restrict__ src,
    const int* __restrict__ dst, const float* __restrict__ v, float* s, int E)
{
    int e = blockIdx.x * blockDim.x + threadIdx.x;
    if (e >= E) return;
    atomicAdd(&s[src[e]], expf(u[e] + v[dst[e]]));
}
__global__ __launch_bounds__(256) void node_pass(
    const int* __restrict__ dest_mask, float* v, float* s, int N)
{
    int n = blockIdx.x * blockDim.x + threadIdx.x;
    if (n >= N) return;
    float sv = s[n];
    v[n] = dest_mask[n] ? 0.0f : (sv > 0.0f ? logf(sv) : NEGV);
    s[n] = 0.0f;
}

// ---------------- host ----------------
extern "C" void kernel_launch(void* const* d_in, const int* in_sizes, int n_in,
                              void* d_out, int out_size, void* d_ws, size_t ws_size,
                              hipStream_t stream)
{
    const float* feats     = (const float*)d_in[0];
    const int*   dest_mask = (const int*)d_in[1];
    const int*   edge_index= (const int*)d_in[2];
    const float* weight    = (const float*)d_in[5];
    const float* bias      = (const float*)d_in[6];

    const int F = in_sizes[5];
    const int E = in_sizes[2] / 2;
    const int N = in_sizes[1];

    const int* src = edge_index;
    const int* dst = edge_index + E;

    float* out   = (float*)d_out;
    float* value = out;
    float* util  = out + N;
    float* prob  = out + (size_t)N + (size_t)E;

    const int eb = (E + 255) / 256;
    const int nb = (N + 255) / 256;

    // K1: util / u
    if (F == 64) {
        long long tt = (long long)E * 16;
        int blocks = (int)((tt + 255) / 256);
        util_kernel64<<<blocks, 256, 0, stream>>>(feats, weight, bias, util, E);
    } else {
        util_kernel<<<eb, 256, 0, stream>>>(feats, weight, bias, util, E, F);
    }

    const int W = (N + NBUCK - 1) / NBUCK;

    // ws layout: hists(B1*NBUCK) | bstarts(NBUCK+2, pad->8B) | edg(int2 E) |
    //            row_ptr(N+1) | ewa(N) | ewb(N) | flags(N_ITERS+1)
    const size_t need_words = (size_t)B1 * NBUCK + (NBUCK + 2)
                            + 2 * (size_t)E + 3 * (size_t)N + 1 + (N_ITERS + 1);
    const size_t need_bytes = need_words * 4;
    const bool pack_ok = (N < (1 << 20)) && (W <= (1 << 12));

    if (d_ws != nullptr && ws_size >= need_bytes && pack_ok) {
        int*   hists   = (int*)d_ws;
        int*   bstarts = hists + (size_t)B1 * NBUCK;
        int2*  edg     = (int2*)(bstarts + (NBUCK + 2));   // 8B-aligned
        int*   row_ptr = (int*)(edg + E);
        float* ewa     = (float*)(row_ptr + (N + 1));
        float* ewb     = ewa + N;
        int*   flags   = (int*)(ewb + N);

        const int chunk = (E + B1 - 1) / B1;
        const size_t fine_lds = (size_t)(2 * CAP + W + 8) * 4;

        bucket_count  <<<B1, 256, 0, stream>>>(src, hists, E, W, chunk);
        bucket_scan   <<<1, NBUCK, 0, stream>>>(hists, bstarts, E);
        bucket_scatter<<<B1, 256, 0, stream>>>(src, dst, util, hists, edg, E, W, chunk);
        fine_sort     <<<NBUCK, 256, fine_lds, stream>>>(bstarts, edg, row_ptr, N, E, W);

        init_exp_kernel<<<nb, 256, 0, stream>>>(dest_mask, ewa, flags, N);

        const int gb = ((N * 8) + 255) / 256;
        float* cur = ewa;
        float* nxt = ewb;
        for (int it = 1; it <= N_ITERS - 1; ++it) {
            iter_exp_conv<<<gb, 256, 0, stream>>>(
                row_ptr, edg, dest_mask, cur, nxt,
                flags + (it - 1), flags + it, N);
            float* t = cur; cur = nxt; nxt = t;
        }
        final_exp_conv<<<gb, 256, 0, stream>>>(
            row_ptr, edg, dest_mask, cur, value, flags + (N_ITERS - 1), N);

        prob_kernel<<<eb, 256, 0, stream>>>(util, src, dst, value, prob, E);
    } else {
        float* s = prob;
        init_pass<<<nb, 256, 0, stream>>>(dest_mask, value, s, N);
        for (int it = 0; it < N_ITERS; ++it) {
            edge_pass<<<eb, 256, 0, stream>>>(util, src, dst, value, s, E);
            node_pass<<<nb, 256, 0, stream>>>(dest_mask, value, s, N);
        }
        prob_kernel<<<eb, 256, 0, stream>>>(util, src, dst, value, prob, E);
    }
}